// Round 4
// baseline (1419.879 us; speedup 1.0000x reference)
//
#include <hip/hip_runtime.h>
#include <hip/hip_bf16.h>
#include <math.h>

#define B_ 8
#define N_ 4096
#define C_ 256
#define DQK_ 32

typedef float f32x4  __attribute__((ext_vector_type(4)));
typedef float f32x16 __attribute__((ext_vector_type(16)));
typedef short bf16x8 __attribute__((ext_vector_type(8)));
typedef short bf16x4 __attribute__((ext_vector_type(4)));

__device__ __forceinline__ short f2bf(float f){
  union { float f; unsigned u; } v; v.f = f;
  unsigned r = v.u + 0x7fffu + ((v.u >> 16) & 1u);
  return (short)(r >> 16);
}

// ---------- kernel 1: weight transpose + cast -> WT[320][256] bf16 ----------
__global__ void cast_wt_kernel(const float* __restrict__ Wq, const float* __restrict__ Wk,
                               const float* __restrict__ Wv, short* __restrict__ WT){
  int n = blockIdx.x;        // 0..319 output channel
  int k = threadIdx.x;       // 0..255 input channel
  float val;
  if (n < 32)       val = Wq[k*32 + n];
  else if (n < 64)  val = Wk[k*32 + (n-32)];
  else              val = Wv[k*256 + (n-64)];
  WT[n*256 + k] = f2bf(val);
}

// ---------- kernel 2: projections -> frag-swizzled q,k,v (unchanged from R3) ----------
__global__ __launch_bounds__(256) void proj_kernel(
    const float* __restrict__ x, const short* __restrict__ WT,
    const float* __restrict__ bq, const float* __restrict__ bk, const float* __restrict__ bv,
    short* __restrict__ qws, short* __restrict__ kws, short* __restrict__ vSw){
  __shared__ __align__(16) short sX[64*264];   // 67584 B
  __shared__ __align__(16) short sT[64*72];    // 9216 B  (q cols 0..31 | k cols 32..63)
  int tid = threadIdx.x;
  int lane = tid & 63, wave = tid >> 6;
  int lane15 = lane & 15, quad = lane >> 4;
  int mbase = blockIdx.x * 64;
  int b = mbase >> 12, kvb = mbase & (N_-1);

  const float* xr = x + (size_t)mbase * C_;
  for (int i = 0; i < 8; i++){
    int s = tid + i*256;
    int row = s >> 5, cg = (s & 31) << 3;
    const f32x4* src = (const f32x4*)(xr + row*C_ + cg);
    f32x4 a = src[0], c = src[1];
    bf16x8 p;
    p[0]=f2bf(a[0]); p[1]=f2bf(a[1]); p[2]=f2bf(a[2]); p[3]=f2bf(a[3]);
    p[4]=f2bf(c[0]); p[5]=f2bf(c[1]); p[6]=f2bf(c[2]); p[7]=f2bf(c[3]);
    *(bf16x8*)(sX + row*264 + cg) = p;
  }
  __syncthreads();

  f32x4 acc[5][4];
  for (int i=0;i<5;i++) for (int mt=0;mt<4;mt++) acc[i][mt] = (f32x4)(0.f);

  for (int kc = 0; kc < 8; kc++){
    bf16x8 afr[4];
    #pragma unroll
    for (int mt=0;mt<4;mt++)
      afr[mt] = *(const bf16x8*)(sX + (mt*16+lane15)*264 + kc*32 + quad*8);
    bf16x8 bfr[5];
    #pragma unroll
    for (int i=0;i<5;i++){
      int t = i*4 + wave;
      bfr[i] = *(const bf16x8*)(WT + (size_t)(t*16+lane15)*256 + kc*32 + quad*8);
    }
    #pragma unroll
    for (int i=0;i<5;i++)
      #pragma unroll
      for (int mt=0;mt<4;mt++)
        acc[i][mt] = __builtin_amdgcn_mfma_f32_16x16x32_bf16(afr[mt], bfr[i], acc[i][mt], 0,0,0);
  }

  #pragma unroll
  for (int i=0;i<5;i++){
    int t = i*4 + wave;
    int n0 = t*16 + lane15;
    float bias = (n0 < 32) ? bq[n0] : (n0 < 64 ? bk[n0-32] : bv[n0-64]);
    if (n0 < 64){
      #pragma unroll
      for (int mt=0;mt<4;mt++)
        #pragma unroll
        for (int r=0;r<4;r++)
          sT[(mt*16 + quad*4 + r)*72 + n0] = f2bf(acc[i][mt][r] + bias);
    } else {
      int ch = n0 - 64, cht = ch >> 5, c5 = ch & 31;
      int lanep = c5 | ((quad & 1) << 5);
      int jo = (quad >> 1) * 4;
      #pragma unroll
      for (int mt=0;mt<4;mt++){
        bf16x4 pk;
        pk[0]=f2bf(acc[i][mt][0]+bias); pk[1]=f2bf(acc[i][mt][1]+bias);
        pk[2]=f2bf(acc[i][mt][2]+bias); pk[3]=f2bf(acc[i][mt][3]+bias);
        size_t off = (size_t)b*1048576 + (size_t)(kvb>>6)*16384
                   + (size_t)(mt*8 + cht)*512 + (size_t)lanep*8 + jo;
        *(bf16x4*)(vSw + off) = pk;
      }
    }
  }
  __syncthreads();

  {
    int qt = tid >> 7, p = (tid >> 6) & 1, ln = tid & 63;
    int row = qt*32 + (ln & 31);
    int dcol = p*16 + (ln >> 5)*8;
    bf16x8 vq = *(const bf16x8*)(sT + row*72 + dcol);
    bf16x8 vk = *(const bf16x8*)(sT + row*72 + 32 + dcol);
    size_t qoff = ((((size_t)b*128 + ((kvb>>5) + qt))*2 + p)*64 + ln)*8;
    *(bf16x8*)(qws + qoff) = vq;
    size_t koff = ((size_t)b*64 + (kvb>>6))*2048 + (size_t)((qt*2 + p)*64 + ln)*8;
    *(bf16x8*)(kws + koff) = vk;
  }
}

// ---------- kernel 3: flash attention + residual ----------
// grid 256 (1 block/CU), block 512 thr = 8 waves (2/SIMD).
// wave w = qt*2+kh: q-tile qt (32 rows x 256 ch), kv-half kh of each 64-chunk.
// acc/accl are kv-partial sums (exact: no max-subtraction) -> LDS pair-reduction at end.
// K frags register-prefetched straight from global (kws frag-ordered); V double-buffered
// in LDS via global_load_lds.
__global__ __launch_bounds__(512, 2) void flash_kernel(
    const float* __restrict__ x, const short* __restrict__ qws, const short* __restrict__ kws,
    const short* __restrict__ vSw, const float* __restrict__ gptr, float* __restrict__ out){
  __shared__ __align__(16) char smem[98304];   // main: sV[2][32KB]; epilogue: 64KB R1 + 32KB RL
  short* sV0 = (short*)smem;
  short* sV1 = (short*)(smem + 32768);
  int tid = threadIdx.x;
  int lane = tid & 63, wave = tid >> 6;
  int l31 = lane & 31, h = lane >> 5;
  int qt = wave >> 1, kh = wave & 1;
  int b = blockIdx.x & 7;
  int q0 = (blockIdx.x >> 3) << 7;

  const short* qb = qws + (size_t)b*131072;
  const short* kb = kws + (size_t)b*131072;
  const short* vb = vSw + (size_t)b*1048576;

  int qtg = (q0 >> 5) + qt;
  bf16x8 qf0 = *(const bf16x8*)(qb + (size_t)((qtg*2+0)*64 + lane)*8);
  bf16x8 qf1 = *(const bf16x8*)(qb + (size_t)((qtg*2+1)*64 + lane)*8);

  // K frag pointers for this wave's kv-half: f = 2*kh + p
  const short* kf0p = kb + (size_t)((2*kh+0)*64 + lane)*8;
  const short* kf1p = kb + (size_t)((2*kh+1)*64 + lane)*8;
  bf16x8 kfc0 = *(const bf16x8*)(kf0p);
  bf16x8 kfc1 = *(const bf16x8*)(kf1p);
  bf16x8 kfn0 = kfc0, kfn1 = kfc1;

  // prologue: stage V chunk 0
  #pragma unroll
  for (int r=0;r<4;r++)
    __builtin_amdgcn_global_load_lds(
      (const __attribute__((address_space(1))) void*)(vb + (size_t)(r*512+tid)*8),
      (__attribute__((address_space(3))) void*)(sV0 + (size_t)(r*512+tid)*8), 16, 0, 0);
  __syncthreads();

  f32x16 acc[8], accl;
  #pragma unroll
  for (int t=0;t<8;t++) acc[t] = (f32x16)(0.f);
  accl = (f32x16)(0.f);
  bf16x8 ones;
  #pragma unroll
  for (int j=0;j<8;j++) ones[j] = (short)0x3F80;

  for (int it=0; it<64; it++){
    short* sVc = (it & 1) ? sV1 : sV0;
    short* sVn = (it & 1) ? sV0 : sV1;
    if (it < 63){
      const short* vsrc = vb + (size_t)(it+1)*16384;
      #pragma unroll
      for (int r=0;r<4;r++)
        __builtin_amdgcn_global_load_lds(
          (const __attribute__((address_space(1))) void*)(vsrc + (size_t)(r*512+tid)*8),
          (__attribute__((address_space(3))) void*)(sVn + (size_t)(r*512+tid)*8), 16, 0, 0);
      kfn0 = *(const bf16x8*)(kf0p + (size_t)(it+1)*2048);
      kfn1 = *(const bf16x8*)(kf1p + (size_t)(it+1)*2048);
    }

    // S^T for this wave's 32 kv x 32 q tile (d=32 in two K=16 phases)
    f32x16 s = __builtin_amdgcn_mfma_f32_32x32x16_bf16(kfc0, qf0, (f32x16)(0.f), 0,0,0);
    s        = __builtin_amdgcn_mfma_f32_32x32x16_bf16(kfc1, qf1, s, 0,0,0);

    // exp (no max-subtraction; |s| < ~35 fits fp32) + pack to A-frags (reg order = pi order)
    bf16x8 pf[2];
    #pragma unroll
    for (int g=0; g<2; g++){
      union { bf16x8 v; unsigned u[4]; } P;
      #pragma unroll
      for (int j=0;j<4;j++){
        float2 e;
        e.x = __expf(s[g*8 + 2*j]);
        e.y = __expf(s[g*8 + 2*j + 1]);
        __hip_bfloat162 t2 = __float22bfloat162_rn(e);
        __builtin_memcpy(&P.u[j], &t2, 4);
      }
      pf[g] = P.v;
    }

    // PV + row-sum over this wave's 2 kv-groups
    #pragma unroll
    for (int g=0; g<2; g++){
      int kvg = 2*kh + g;
      const short* base = sVc + kvg*4096;
      #pragma unroll
      for (int cht=0; cht<8; cht++){
        bf16x8 vf = *(const bf16x8*)(base + (cht*64 + lane)*8);
        acc[cht] = __builtin_amdgcn_mfma_f32_32x32x16_bf16(pf[g], vf, acc[cht], 0,0,0);
      }
      accl = __builtin_amdgcn_mfma_f32_32x32x16_bf16(pf[g], ones, accl, 0,0,0);
    }
    kfc0 = kfn0; kfc1 = kfn1;
    __syncthreads();
  }

  // ---- pair reduction over kv-halves (partner = wave^1), 2 phases in 96KB LDS ----
  float* R1 = (float*)smem;              // [wave][j(2)][i(16)][lane]  = 64 KB
  float* RL = (float*)(smem + 65536);    // [wave][i(16)][lane]        = 32 KB
  int myB = kh*4, opB = 4 - kh*4;
  int pw = wave ^ 1;
  #pragma unroll
  for (int j=0;j<2;j++)
    #pragma unroll
    for (int i=0;i<16;i++)
      R1[wave*2048 + j*1024 + i*64 + lane] = acc[opB+j][i];
  #pragma unroll
  for (int i=0;i<16;i++)
    RL[wave*1024 + i*64 + lane] = accl[i];
  __syncthreads();
  #pragma unroll
  for (int j=0;j<2;j++)
    #pragma unroll
    for (int i=0;i<16;i++)
      acc[myB+j][i] += R1[pw*2048 + j*1024 + i*64 + lane];
  #pragma unroll
  for (int i=0;i<16;i++)
    accl[i] += RL[pw*1024 + i*64 + lane];
  __syncthreads();
  #pragma unroll
  for (int j=0;j<2;j++)
    #pragma unroll
    for (int i=0;i<16;i++)
      R1[wave*2048 + j*1024 + i*64 + lane] = acc[opB+2+j][i];
  __syncthreads();
  #pragma unroll
  for (int j=0;j<2;j++)
    #pragma unroll
    for (int i=0;i<16;i++)
      acc[myB+2+j][i] += R1[pw*2048 + j*1024 + i*64 + lane];

  // ---- epilogue: out = gamma * O/l + x ; wave owns rows [q0+32qt,+32) x ch [128kh,+128) ----
  float g = *gptr;
  const float* xb = x + ((size_t)b*N_ + q0 + qt*32)*C_;
  float*       ob = out + ((size_t)b*N_ + q0 + qt*32)*C_;
  #pragma unroll
  for (int i=0;i<16;i++){
    int q = (i&3) + 8*(i>>2) + 4*h;
    float rv = 1.f / accl[i];
    #pragma unroll
    for (int ct=0; ct<4; ct++){
      int cht = myB + ct;
      int ch = cht*32 + l31;
      ob[(size_t)q*C_ + ch] = g*(acc[cht][i]*rv) + xb[(size_t)q*C_ + ch];
    }
  }
}

extern "C" void kernel_launch(void* const* d_in, const int* in_sizes, int n_in,
                              void* d_out, int out_size, void* d_ws, size_t ws_size,
                              hipStream_t stream){
  const float* x  = (const float*)d_in[0];
  const float* Wq = (const float*)d_in[1];
  const float* bq = (const float*)d_in[2];
  const float* Wk = (const float*)d_in[3];
  const float* bk = (const float*)d_in[4];
  const float* Wv = (const float*)d_in[5];
  const float* bv = (const float*)d_in[6];
  const float* gm = (const float*)d_in[7];
  float* out = (float*)d_out;
  char* ws = (char*)d_ws;
  short* WT  = (short*)ws;                               // 163840 B
  short* qws = (short*)(ws + 163840);                    // 2097152 B
  short* kws = (short*)(ws + 163840 + 2097152);          // 2097152 B
  short* vSw = (short*)(ws + 163840 + 2*2097152);        // 16777216 B

  cast_wt_kernel<<<dim3(320), dim3(256), 0, stream>>>(Wq, Wk, Wv, WT);
  proj_kernel<<<dim3(512), dim3(256), 0, stream>>>(x, WT, bq, bk, bv, qws, kws, vSw);
  flash_kernel<<<dim3(256), dim3(512), 0, stream>>>(x, qws, kws, vSw, gm, out);
}

// Round 5
// 190.496 us; speedup vs baseline: 7.4536x; 7.4536x over previous
//
#include <hip/hip_runtime.h>
#include <hip/hip_bf16.h>
#include <math.h>

#define B_ 8
#define N_ 4096
#define C_ 256
#define DQK_ 32

typedef float f32x4  __attribute__((ext_vector_type(4)));
typedef float f32x16 __attribute__((ext_vector_type(16)));
typedef short bf16x8 __attribute__((ext_vector_type(8)));
typedef short bf16x4 __attribute__((ext_vector_type(4)));

__device__ __forceinline__ short f2bf(float f){
  union { float f; unsigned u; } v; v.f = f;
  unsigned r = v.u + 0x7fffu + ((v.u >> 16) & 1u);
  return (short)(r >> 16);
}

// ---------- kernel 1: weight transpose + cast -> WT[320][256] bf16 ----------
__global__ void cast_wt_kernel(const float* __restrict__ Wq, const float* __restrict__ Wk,
                               const float* __restrict__ Wv, short* __restrict__ WT){
  int n = blockIdx.x;        // 0..319 output channel
  int k = threadIdx.x;       // 0..255 input channel
  float val;
  if (n < 32)       val = Wq[k*32 + n];
  else if (n < 64)  val = Wk[k*32 + (n-32)];
  else              val = Wv[k*256 + (n-64)];
  WT[n*256 + k] = f2bf(val);
}

// ---------- kernel 2: projections -> frag-swizzled q,k,v ----------
__global__ __launch_bounds__(256) void proj_kernel(
    const float* __restrict__ x, const short* __restrict__ WT,
    const float* __restrict__ bq, const float* __restrict__ bk, const float* __restrict__ bv,
    short* __restrict__ qws, short* __restrict__ kws, short* __restrict__ vSw){
  __shared__ __align__(16) short sX[64*264];   // 67584 B
  __shared__ __align__(16) short sT[64*72];    // 9216 B  (q cols 0..31 | k cols 32..63)
  int tid = threadIdx.x;
  int lane = tid & 63, wave = tid >> 6;
  int lane15 = lane & 15, quad = lane >> 4;
  int mbase = blockIdx.x * 64;
  int b = mbase >> 12, kvb = mbase & (N_-1);

  const float* xr = x + (size_t)mbase * C_;
  for (int i = 0; i < 8; i++){
    int s = tid + i*256;
    int row = s >> 5, cg = (s & 31) << 3;
    const f32x4* src = (const f32x4*)(xr + row*C_ + cg);
    f32x4 a = src[0], c = src[1];
    bf16x8 p;
    p[0]=f2bf(a[0]); p[1]=f2bf(a[1]); p[2]=f2bf(a[2]); p[3]=f2bf(a[3]);
    p[4]=f2bf(c[0]); p[5]=f2bf(c[1]); p[6]=f2bf(c[2]); p[7]=f2bf(c[3]);
    *(bf16x8*)(sX + row*264 + cg) = p;
  }
  __syncthreads();

  f32x4 acc[5][4];
  for (int i=0;i<5;i++) for (int mt=0;mt<4;mt++) acc[i][mt] = (f32x4)(0.f);

  for (int kc = 0; kc < 8; kc++){
    bf16x8 afr[4];
    #pragma unroll
    for (int mt=0;mt<4;mt++)
      afr[mt] = *(const bf16x8*)(sX + (mt*16+lane15)*264 + kc*32 + quad*8);
    bf16x8 bfr[5];
    #pragma unroll
    for (int i=0;i<5;i++){
      int t = i*4 + wave;
      bfr[i] = *(const bf16x8*)(WT + (size_t)(t*16+lane15)*256 + kc*32 + quad*8);
    }
    #pragma unroll
    for (int i=0;i<5;i++)
      #pragma unroll
      for (int mt=0;mt<4;mt++)
        acc[i][mt] = __builtin_amdgcn_mfma_f32_16x16x32_bf16(afr[mt], bfr[i], acc[i][mt], 0,0,0);
  }

  #pragma unroll
  for (int i=0;i<5;i++){
    int t = i*4 + wave;
    int n0 = t*16 + lane15;
    float bias = (n0 < 32) ? bq[n0] : (n0 < 64 ? bk[n0-32] : bv[n0-64]);
    if (n0 < 64){
      #pragma unroll
      for (int mt=0;mt<4;mt++)
        #pragma unroll
        for (int r=0;r<4;r++)
          sT[(mt*16 + quad*4 + r)*72 + n0] = f2bf(acc[i][mt][r] + bias);
    } else {
      int ch = n0 - 64, cht = ch >> 5, c5 = ch & 31;
      int lanep = c5 | ((quad & 1) << 5);
      int jo = (quad >> 1) * 4;
      #pragma unroll
      for (int mt=0;mt<4;mt++){
        bf16x4 pk;
        pk[0]=f2bf(acc[i][mt][0]+bias); pk[1]=f2bf(acc[i][mt][1]+bias);
        pk[2]=f2bf(acc[i][mt][2]+bias); pk[3]=f2bf(acc[i][mt][3]+bias);
        size_t off = (size_t)b*1048576 + (size_t)(kvb>>6)*16384
                   + (size_t)(mt*8 + cht)*512 + (size_t)lanep*8 + jo;
        *(bf16x4*)(vSw + off) = pk;
      }
    }
  }
  __syncthreads();

  {
    int qt = tid >> 7, p = (tid >> 6) & 1, ln = tid & 63;
    int row = qt*32 + (ln & 31);
    int dcol = p*16 + (ln >> 5)*8;
    bf16x8 vq = *(const bf16x8*)(sT + row*72 + dcol);
    bf16x8 vk = *(const bf16x8*)(sT + row*72 + 32 + dcol);
    size_t qoff = ((((size_t)b*128 + ((kvb>>5) + qt))*2 + p)*64 + ln)*8;
    *(bf16x8*)(qws + qoff) = vq;
    size_t koff = ((size_t)b*64 + (kvb>>6))*2048 + (size_t)((qt*2 + p)*64 + ln)*8;
    *(bf16x8*)(kws + koff) = vk;
  }
}

// ---------- kernel 3: flash attention + residual ----------
// grid 256 (1 block/CU), block 512 thr = 8 waves (2/SIMD).
// wave w = qt*2+kh: q-tile qt (32 rows x 256 ch), kv-half kh of each 64-chunk.
// ALL acc indices are compile-time constants (R4's dynamic indices spilled acc to
// scratch -> 6.6 GB HBM traffic). kh-dependent paths use wave-uniform if/else with
// barriers OUTSIDE the branches.
__global__ __launch_bounds__(512, 2) void flash_kernel(
    const float* __restrict__ x, const short* __restrict__ qws, const short* __restrict__ kws,
    const short* __restrict__ vSw, const float* __restrict__ gptr, float* __restrict__ out){
  __shared__ __align__(16) char smem[98304];   // main: sV[2][32KB]; epilogue: 64KB R1 + 32KB RL
  short* sV0 = (short*)smem;
  short* sV1 = (short*)(smem + 32768);
  int tid = threadIdx.x;
  int lane = tid & 63, wave = tid >> 6;
  int l31 = lane & 31, h = lane >> 5;
  int qt = wave >> 1, kh = wave & 1;
  int b = blockIdx.x & 7;
  int q0 = (blockIdx.x >> 3) << 7;

  const short* qb = qws + (size_t)b*131072;
  const short* kb = kws + (size_t)b*131072;
  const short* vb = vSw + (size_t)b*1048576;

  int qtg = (q0 >> 5) + qt;
  bf16x8 qf0 = *(const bf16x8*)(qb + (size_t)((qtg*2+0)*64 + lane)*8);
  bf16x8 qf1 = *(const bf16x8*)(qb + (size_t)((qtg*2+1)*64 + lane)*8);

  const short* kf0p = kb + (size_t)((2*kh+0)*64 + lane)*8;
  const short* kf1p = kb + (size_t)((2*kh+1)*64 + lane)*8;
  bf16x8 kfc0 = *(const bf16x8*)(kf0p);
  bf16x8 kfc1 = *(const bf16x8*)(kf1p);
  bf16x8 kfn0 = kfc0, kfn1 = kfc1;

  #pragma unroll
  for (int r=0;r<4;r++)
    __builtin_amdgcn_global_load_lds(
      (const __attribute__((address_space(1))) void*)(vb + (size_t)(r*512+tid)*8),
      (__attribute__((address_space(3))) void*)(sV0 + (size_t)(r*512+tid)*8), 16, 0, 0);
  __syncthreads();

  f32x16 acc[8], accl;
  #pragma unroll
  for (int t=0;t<8;t++) acc[t] = (f32x16)(0.f);
  accl = (f32x16)(0.f);
  bf16x8 ones;
  #pragma unroll
  for (int j=0;j<8;j++) ones[j] = (short)0x3F80;

  for (int it=0; it<64; it++){
    short* sVc = (it & 1) ? sV1 : sV0;
    short* sVn = (it & 1) ? sV0 : sV1;
    if (it < 63){
      const short* vsrc = vb + (size_t)(it+1)*16384;
      #pragma unroll
      for (int r=0;r<4;r++)
        __builtin_amdgcn_global_load_lds(
          (const __attribute__((address_space(1))) void*)(vsrc + (size_t)(r*512+tid)*8),
          (__attribute__((address_space(3))) void*)(sVn + (size_t)(r*512+tid)*8), 16, 0, 0);
      kfn0 = *(const bf16x8*)(kf0p + (size_t)(it+1)*2048);
      kfn1 = *(const bf16x8*)(kf1p + (size_t)(it+1)*2048);
    }

    // S^T for this wave's 32 kv x 32 q tile (d=32 in two K=16 phases)
    f32x16 s = __builtin_amdgcn_mfma_f32_32x32x16_bf16(kfc0, qf0, (f32x16)(0.f), 0,0,0);
    s        = __builtin_amdgcn_mfma_f32_32x32x16_bf16(kfc1, qf1, s, 0,0,0);

    // exp (no max-subtraction; |s| < ~35 fits fp32) + pack to A-frags (reg order = pi order)
    bf16x8 pf[2];
    #pragma unroll
    for (int g=0; g<2; g++){
      union { bf16x8 v; unsigned u[4]; } P;
      #pragma unroll
      for (int j=0;j<4;j++){
        float2 e;
        e.x = __expf(s[g*8 + 2*j]);
        e.y = __expf(s[g*8 + 2*j + 1]);
        __hip_bfloat162 t2 = __float22bfloat162_rn(e);
        __builtin_memcpy(&P.u[j], &t2, 4);
      }
      pf[g] = P.v;
    }

    // PV + row-sum over this wave's 2 kv-groups (LDS base kh-dependent = address, ok)
    #pragma unroll
    for (int g=0; g<2; g++){
      const short* base = sVc + (2*kh + g)*4096;
      #pragma unroll
      for (int cht=0; cht<8; cht++){
        bf16x8 vf = *(const bf16x8*)(base + (cht*64 + lane)*8);
        acc[cht] = __builtin_amdgcn_mfma_f32_32x32x16_bf16(pf[g], vf, acc[cht], 0,0,0);
      }
      accl = __builtin_amdgcn_mfma_f32_32x32x16_bf16(pf[g], ones, accl, 0,0,0);
    }
    kfc0 = kfn0; kfc1 = kfn1;
    __syncthreads();
  }

  // ---- pair reduction over kv-halves (partner wave = wave^1), constant reg indices ----
  float* R1 = (float*)smem;              // [wave][j(2)][i(16)][lane]  = 64 KB
  float* RL = (float*)(smem + 65536);    // [wave][i(16)][lane]        = 32 KB
  int pw = wave ^ 1;
  // phase 1: exchange first 2 accs of the half I'm NOT keeping, plus accl
  if (kh == 0){
    #pragma unroll
    for (int i=0;i<16;i++){ R1[wave*2048 + i*64 + lane] = acc[4][i];
                            R1[wave*2048 + 1024 + i*64 + lane] = acc[5][i]; }
  } else {
    #pragma unroll
    for (int i=0;i<16;i++){ R1[wave*2048 + i*64 + lane] = acc[0][i];
                            R1[wave*2048 + 1024 + i*64 + lane] = acc[1][i]; }
  }
  #pragma unroll
  for (int i=0;i<16;i++) RL[wave*1024 + i*64 + lane] = accl[i];
  __syncthreads();
  if (kh == 0){
    #pragma unroll
    for (int i=0;i<16;i++){ acc[0][i] += R1[pw*2048 + i*64 + lane];
                            acc[1][i] += R1[pw*2048 + 1024 + i*64 + lane]; }
  } else {
    #pragma unroll
    for (int i=0;i<16;i++){ acc[4][i] += R1[pw*2048 + i*64 + lane];
                            acc[5][i] += R1[pw*2048 + 1024 + i*64 + lane]; }
  }
  #pragma unroll
  for (int i=0;i<16;i++) accl[i] += RL[pw*1024 + i*64 + lane];
  __syncthreads();
  // phase 2: exchange remaining 2 accs
  if (kh == 0){
    #pragma unroll
    for (int i=0;i<16;i++){ R1[wave*2048 + i*64 + lane] = acc[6][i];
                            R1[wave*2048 + 1024 + i*64 + lane] = acc[7][i]; }
  } else {
    #pragma unroll
    for (int i=0;i<16;i++){ R1[wave*2048 + i*64 + lane] = acc[2][i];
                            R1[wave*2048 + 1024 + i*64 + lane] = acc[3][i]; }
  }
  __syncthreads();
  if (kh == 0){
    #pragma unroll
    for (int i=0;i<16;i++){ acc[2][i] += R1[pw*2048 + i*64 + lane];
                            acc[3][i] += R1[pw*2048 + 1024 + i*64 + lane]; }
  } else {
    #pragma unroll
    for (int i=0;i<16;i++){ acc[6][i] += R1[pw*2048 + i*64 + lane];
                            acc[7][i] += R1[pw*2048 + 1024 + i*64 + lane]; }
  }

  // ---- epilogue: out = gamma*O/l + x ; wave owns rows [q0+32qt,+32) x ch [128kh,+128) ----
  float g = *gptr;
  const float* xb = x + ((size_t)b*N_ + q0 + qt*32)*C_;
  float*       ob = out + ((size_t)b*N_ + q0 + qt*32)*C_;
  if (kh == 0){
    #pragma unroll
    for (int i=0;i<16;i++){
      int q = (i&3) + 8*(i>>2) + 4*h;
      float rv = 1.f / accl[i];
      #pragma unroll
      for (int ct=0; ct<4; ct++){
        int ch = ct*32 + l31;
        ob[(size_t)q*C_ + ch] = g*(acc[ct][i]*rv) + xb[(size_t)q*C_ + ch];
      }
    }
  } else {
    #pragma unroll
    for (int i=0;i<16;i++){
      int q = (i&3) + 8*(i>>2) + 4*h;
      float rv = 1.f / accl[i];
      #pragma unroll
      for (int ct=0; ct<4; ct++){
        int ch = (4+ct)*32 + l31;
        ob[(size_t)q*C_ + ch] = g*(acc[4+ct][i]*rv) + xb[(size_t)q*C_ + ch];
      }
    }
  }
}

extern "C" void kernel_launch(void* const* d_in, const int* in_sizes, int n_in,
                              void* d_out, int out_size, void* d_ws, size_t ws_size,
                              hipStream_t stream){
  const float* x  = (const float*)d_in[0];
  const float* Wq = (const float*)d_in[1];
  const float* bq = (const float*)d_in[2];
  const float* Wk = (const float*)d_in[3];
  const float* bk = (const float*)d_in[4];
  const float* Wv = (const float*)d_in[5];
  const float* bv = (const float*)d_in[6];
  const float* gm = (const float*)d_in[7];
  float* out = (float*)d_out;
  char* ws = (char*)d_ws;
  short* WT  = (short*)ws;                               // 163840 B
  short* qws = (short*)(ws + 163840);                    // 2097152 B
  short* kws = (short*)(ws + 163840 + 2097152);          // 2097152 B
  short* vSw = (short*)(ws + 163840 + 2*2097152);        // 16777216 B

  cast_wt_kernel<<<dim3(320), dim3(256), 0, stream>>>(Wq, Wk, Wv, WT);
  proj_kernel<<<dim3(512), dim3(256), 0, stream>>>(x, WT, bq, bk, bv, qws, kws, vSw);
  flash_kernel<<<dim3(256), dim3(512), 0, stream>>>(x, qws, kws, vSw, gm, out);
}